// Round 1
// baseline (564.460 us; speedup 1.0000x reference)
//
#include <hip/hip_runtime.h>

// GeometricEmbedding: per-pair RBF (3.2M x 32) + cutoff-weighted spherical
// harmonics segment-summed into chi (100k x 8). Write-BW bound (~410 MB rbf).

#define NRBF 32
constexpr float R_CUT   = 5.0f;
constexpr float WIDTH   = R_CUT / NRBF;            // 0.15625
constexpr float INV_W   = 1.0f / WIDTH;
constexpr float CSPACE  = R_CUT / (NRBF - 1);      // linspace(0,5,32) spacing
constexpr float PI_F    = 3.14159265358979323846f;
constexpr float C1  = 0.48860251190291992f;        // sqrt(3/(4pi))
constexpr float C2A = 1.09254843059207907f;        // 0.5*sqrt(15/pi)
constexpr float C2B = 0.31539156525252005f;        // 0.25*sqrt(5/pi)
constexpr float C2C = 0.54627421529603953f;        // 0.25*sqrt(15/pi)

__global__ __launch_bounds__(256) void geom_pairs_kernel(
    const float* __restrict__ R,
    const float* __restrict__ pair_mask,
    const float* __restrict__ point_mask,
    const int*   __restrict__ idx_i,
    const int*   __restrict__ idx_j,
    float* __restrict__ rbf_out,
    float* __restrict__ chi_out,
    int n_pairs)
{
    const int p    = blockIdx.x * blockDim.x + threadIdx.x;
    const int lane = threadIdx.x & 63;

    int   seg = -1;          // idx_i value; -1 for inactive lanes
    float w[8];
    #pragma unroll
    for (int c = 0; c < 8; ++c) w[c] = 0.0f;

    if (p < n_pairs) {
        const int   i = idx_i[p];
        const int   j = idx_j[p];
        const float m = pair_mask[p];
        seg = i;

        // r_ij = (R[j] - R[i]) * m   (R is 1.2 MB -> L2-resident gathers)
        const float rx = (R[3*j+0] - R[3*i+0]) * m;
        const float ry = (R[3*j+1] - R[3*i+1]) * m;
        const float rz = (R[3*j+2] - R[3*i+2]) * m;

        const float sq = rx*rx + ry*ry + rz*rz;
        float d = (sq == 0.0f) ? 0.0f : sqrtf(sq);
        d *= m;

        // --- RBF: exp(-0.5*((d - c_k)/width)^2) * m, 32 values ---
        float rbf[NRBF];
        #pragma unroll
        for (int k = 0; k < NRBF; ++k) {
            const float t = (d - (float)k * CSPACE) * INV_W;
            rbf[k] = __expf(-0.5f * t * t) * m;
        }
        // per-thread contiguous 128B chunk; wave covers 8KB contiguous
        float4* dst = (float4*)(rbf_out + (size_t)p * NRBF);
        #pragma unroll
        for (int k = 0; k < NRBF/4; ++k) {
            dst[k] = make_float4(rbf[4*k+0], rbf[4*k+1], rbf[4*k+2], rbf[4*k+3]);
        }

        // --- cutoff envelope ---
        float phi = 0.5f * (__cosf(PI_F * d * (1.0f/R_CUT)) + 1.0f);
        phi *= (d < R_CUT) ? 1.0f : 0.0f;
        phi *= m;

        // --- unit vector (ref: 0 when d==0) ---
        const float inv_d = (d != 0.0f) ? (1.0f / d) : 0.0f;
        const float ux = rx * inv_d * m;
        const float uy = ry * inv_d * m;
        const float uz = rz * inv_d * m;

        // --- sph l1,l2 (note: l2[2] = C2B*(3z^2-1) NOT zero-guarded, *m) ---
        float s[8];
        s[0] = C1  * uy;
        s[1] = C1  * uz;
        s[2] = C1  * ux;
        s[3] = C2A * ux * uy;
        s[4] = C2A * uy * uz;
        s[5] = C2B * (3.0f * uz * uz - 1.0f) * m;  // needs explicit mask
        s[6] = C2A * ux * uz;
        s[7] = C2C * (ux * ux - uy * uy);

        const float scale = phi * point_mask[i];   // fold point_mask/LAMBDA per-term
        #pragma unroll
        for (int c = 0; c < 8; ++c) w[c] = s[c] * scale;
    }

    // --- wave-level segmented reduction over sorted idx_i runs ---
    #pragma unroll
    for (int off = 1; off < 64; off <<= 1) {
        const int  oseg = __shfl_down(seg, off, 64);
        const bool ok   = (lane + off < 64) && (oseg == seg);
        #pragma unroll
        for (int c = 0; c < 8; ++c) {
            const float ow = __shfl_down(w[c], off, 64);
            if (ok) w[c] += ow;
        }
    }
    const int  pseg = __shfl_up(seg, 1, 64);
    const bool head = (lane == 0) || (pseg != seg);
    if (head && seg >= 0) {
        float* dst = chi_out + (size_t)seg * 8;
        #pragma unroll
        for (int c = 0; c < 8; ++c) unsafeAtomicAdd(dst + c, w[c]);
    }
}

extern "C" void kernel_launch(void* const* d_in, const int* in_sizes, int n_in,
                              void* d_out, int out_size, void* d_ws, size_t ws_size,
                              hipStream_t stream) {
    const float* R          = (const float*)d_in[0];
    const float* pair_mask  = (const float*)d_in[1];
    const float* point_mask = (const float*)d_in[2];
    const int*   idx_i      = (const int*)d_in[3];
    const int*   idx_j      = (const int*)d_in[4];
    // d_in[5] = z (unused by reference outputs)

    const int n_pairs = in_sizes[1];   // pair_mask length
    const int n       = in_sizes[2];   // point_mask length

    float* rbf_out = (float*)d_out;                       // [n_pairs, 32]
    float* chi_out = rbf_out + (size_t)n_pairs * NRBF;    // [n, 8]

    // harness poisons d_out with 0xAA before every timed launch
    hipMemsetAsync(chi_out, 0, (size_t)n * 8 * sizeof(float), stream);

    const int block = 256;
    const int grid  = (n_pairs + block - 1) / block;
    geom_pairs_kernel<<<grid, block, 0, stream>>>(
        R, pair_mask, point_mask, idx_i, idx_j, rbf_out, chi_out, n_pairs);
}

// Round 2
// 489.521 us; speedup vs baseline: 1.1531x; 1.1531x over previous
//
#include <hip/hip_runtime.h>

// GeometricEmbedding: per-pair RBF (3.2M x 32, write-BW bound ~410 MB) +
// cutoff-weighted spherical harmonics segment-summed into chi (100k x 8).
//
// R1: rbf phase restructured to 8-lanes-per-pair so global stores are
// fully coalesced (16B lane stride) instead of 128B-stride partial-line
// writes. d/m broadcast to the 8-lane groups via __shfl; exp count
// unchanged; rbf[32] register array eliminated.

#define NRBF 32
constexpr float R_CUT   = 5.0f;
constexpr float WIDTH   = R_CUT / NRBF;            // 0.15625
constexpr float INV_W   = 1.0f / WIDTH;            // 6.4
constexpr float CSPACE  = R_CUT / (NRBF - 1);      // linspace(0,5,32) spacing
constexpr float PI_F    = 3.14159265358979323846f;
constexpr float LOG2E   = 1.44269504088896340736f;
// exp(-0.5*((d-c)/W)^2) == exp2(A*(d-c)^2), A = -0.5*log2(e)/W^2
constexpr float EXP2_A  = -0.5f * LOG2E * INV_W * INV_W;
constexpr float C1  = 0.48860251190291992f;        // sqrt(3/(4pi))
constexpr float C2A = 1.09254843059207907f;        // 0.5*sqrt(15/pi)
constexpr float C2B = 0.31539156525252005f;        // 0.25*sqrt(5/pi)
constexpr float C2C = 0.54627421529603953f;        // 0.25*sqrt(15/pi)

__global__ __launch_bounds__(256) void geom_pairs_kernel(
    const float* __restrict__ R,
    const float* __restrict__ pair_mask,
    const float* __restrict__ point_mask,
    const int*   __restrict__ idx_i,
    const int*   __restrict__ idx_j,
    float* __restrict__ rbf_out,
    float* __restrict__ chi_out,
    int n_pairs)
{
    const int p    = blockIdx.x * blockDim.x + threadIdx.x;
    const int lane = threadIdx.x & 63;

    int   seg = -1;          // idx_i value; -1 for inactive lanes
    float d = 0.0f, m = 0.0f;
    float w[8];
    #pragma unroll
    for (int c = 0; c < 8; ++c) w[c] = 0.0f;

    if (p < n_pairs) {
        const int i = idx_i[p];
        const int j = idx_j[p];
        m   = pair_mask[p];
        seg = i;

        // r_ij = (R[j] - R[i]) * m   (R is 1.2 MB -> L2-resident gathers)
        const float rx = (R[3*j+0] - R[3*i+0]) * m;
        const float ry = (R[3*j+1] - R[3*i+1]) * m;
        const float rz = (R[3*j+2] - R[3*i+2]) * m;

        const float sq = rx*rx + ry*ry + rz*rz;
        d = sqrtf(sq) * m;   // sqrtf(0)==0, matches ref's zero-guard

        // --- cutoff envelope ---
        float phi = 0.5f * (__cosf(PI_F * d * (1.0f/R_CUT)) + 1.0f);
        phi *= (d < R_CUT) ? 1.0f : 0.0f;
        phi *= m;

        // --- unit vector (ref: 0 when d==0) ---
        const float inv_d = (d != 0.0f) ? (1.0f / d) : 0.0f;
        const float ux = rx * inv_d * m;
        const float uy = ry * inv_d * m;
        const float uz = rz * inv_d * m;

        // --- sph l1,l2 (l2[2] = C2B*(3z^2-1) NOT zero-guarded in ref, *m) ---
        float s[8];
        s[0] = C1  * uy;
        s[1] = C1  * uz;
        s[2] = C1  * ux;
        s[3] = C2A * ux * uy;
        s[4] = C2A * uy * uz;
        s[5] = C2B * (3.0f * uz * uz - 1.0f) * m;  // needs explicit mask
        s[6] = C2A * ux * uz;
        s[7] = C2C * (ux * ux - uy * uy);

        const float scale = phi * point_mask[i];   // fold point_mask/LAMBDA per-term
        #pragma unroll
        for (int c = 0; c < 8; ++c) w[c] = s[c] * scale;
    }

    // --- rbf phase: 8 lanes per pair, fully coalesced float4 stores ---
    // Wave covers pairs [p-lane, p-lane+64) in 8 iterations of 8 pairs.
    {
        const long long wbase = (long long)(p - lane);  // wave-uniform
        const int sub   = lane & 7;        // which 4-elem group this lane stores
        const int grp   = lane >> 3;       // which pair within the iteration
        #pragma unroll
        for (int it = 0; it < 8; ++it) {
            const int srcl = it * 8 + grp;
            const float dd = __shfl(d, srcl, 64);
            const float mm = __shfl(m, srcl, 64);
            const long long pr = wbase + srcl;
            if (pr < (long long)n_pairs) {
                float v[4];
                #pragma unroll
                for (int q = 0; q < 4; ++q) {
                    const int   k  = 4 * sub + q;
                    const float dc = dd - (float)k * CSPACE;
                    v[q] = __builtin_amdgcn_exp2f(EXP2_A * dc * dc) * mm;
                }
                float4* dst = (float4*)(rbf_out + pr * NRBF + 4 * sub);
                *dst = make_float4(v[0], v[1], v[2], v[3]);
            }
        }
    }

    // --- wave-level segmented reduction over sorted idx_i runs ---
    #pragma unroll
    for (int off = 1; off < 64; off <<= 1) {
        const int  oseg = __shfl_down(seg, off, 64);
        const bool ok   = (lane + off < 64) && (oseg == seg);
        #pragma unroll
        for (int c = 0; c < 8; ++c) {
            const float ow = __shfl_down(w[c], off, 64);
            if (ok) w[c] += ow;
        }
    }
    const int  pseg = __shfl_up(seg, 1, 64);
    const bool head = (lane == 0) || (pseg != seg);
    if (head && seg >= 0) {
        float* dst = chi_out + (size_t)seg * 8;
        #pragma unroll
        for (int c = 0; c < 8; ++c) unsafeAtomicAdd(dst + c, w[c]);
    }
}

extern "C" void kernel_launch(void* const* d_in, const int* in_sizes, int n_in,
                              void* d_out, int out_size, void* d_ws, size_t ws_size,
                              hipStream_t stream) {
    const float* R          = (const float*)d_in[0];
    const float* pair_mask  = (const float*)d_in[1];
    const float* point_mask = (const float*)d_in[2];
    const int*   idx_i      = (const int*)d_in[3];
    const int*   idx_j      = (const int*)d_in[4];
    // d_in[5] = z (unused by reference outputs)

    const int n_pairs = in_sizes[1];   // pair_mask length
    const int n       = in_sizes[2];   // point_mask length

    float* rbf_out = (float*)d_out;                       // [n_pairs, 32]
    float* chi_out = rbf_out + (size_t)n_pairs * NRBF;    // [n, 8]

    // harness poisons d_out with 0xAA before every timed launch
    hipMemsetAsync(chi_out, 0, (size_t)n * 8 * sizeof(float), stream);

    const int block = 256;
    const int grid  = (n_pairs + block - 1) / block;
    geom_pairs_kernel<<<grid, block, 0, stream>>>(
        R, pair_mask, point_mask, idx_i, idx_j, rbf_out, chi_out, n_pairs);
}